// Round 1
// baseline (555.671 us; speedup 1.0000x reference)
//
#include <hip/hip_runtime.h>

// Problem constants (B,T,U,D,V) = (2,512,128,512,1024)
#define BB 2
#define TT 512
#define UU 128
#define DD 512
#define VV 1024

typedef float float4v __attribute__((ext_vector_type(4)));

// ---------------------------------------------------------------------------
// Kernel 1: both projections in one launch.
//   Cenc[m][v] = sum_k Enc[m][k] * W[v][k]        (m in [0,1024))
//   Cdec[m][v] = sum_k Dec[m][k] * W[v][512+k]    (m in [0,256))
// Tiles: BM=64, BN=64, BK=32; 256 threads; each thread 4x4 outputs.
// Grid: 256 enc tiles + 64 dec tiles = 320 blocks.
// ---------------------------------------------------------------------------
__global__ __launch_bounds__(256) void proj_gemm_kernel(
    const float* __restrict__ Aenc,
    const float* __restrict__ Adec,
    const float* __restrict__ W,
    float* __restrict__ Cenc,
    float* __restrict__ Cdec)
{
    __shared__ float sA[32][68];   // [k][m], stride 68 floats = 272B (16B aligned)
    __shared__ float sB[32][68];   // [k][v]

    int bid = blockIdx.x;
    const float* A; const float* Wp; float* C;
    int tile_m, tile_n;
    if (bid < 256) {
        A = Aenc; Wp = W; C = Cenc;
        tile_m = bid >> 4; tile_n = bid & 15;
    } else {
        int b2 = bid - 256;
        A = Adec; Wp = W + DD; C = Cdec;   // dec uses W[:, 512:]
        tile_m = b2 >> 4; tile_n = b2 & 15;
    }
    const int row0 = tile_m * 64;
    const int col0 = tile_n * 64;
    const int tid = threadIdx.x;
    const int tx = tid & 15;   // n-groups of 4
    const int ty = tid >> 4;   // m-groups of 4

    float acc[4][4] = {};

    for (int k0 = 0; k0 < DD; k0 += 32) {
        // stage A-tile (64x32) and W-tile (64x32), transposed into LDS [k][row]
        #pragma unroll
        for (int i = 0; i < 2; ++i) {
            int idx = tid + i * 256;        // 0..511
            int r  = idx >> 3;              // 0..63 tile row
            int kq = idx & 7;               // float4 index along k
            float4v va = *(const float4v*)&A[(size_t)(row0 + r) * DD + k0 + kq * 4];
            sA[kq*4+0][r] = va.x;
            sA[kq*4+1][r] = va.y;
            sA[kq*4+2][r] = va.z;
            sA[kq*4+3][r] = va.w;
            float4v vw = *(const float4v*)&Wp[(size_t)(col0 + r) * (2*DD) + k0 + kq * 4];
            sB[kq*4+0][r] = vw.x;
            sB[kq*4+1][r] = vw.y;
            sB[kq*4+2][r] = vw.z;
            sB[kq*4+3][r] = vw.w;
        }
        __syncthreads();

        #pragma unroll
        for (int k = 0; k < 32; ++k) {
            float4v a = *(const float4v*)&sA[k][ty * 4];
            float4v b = *(const float4v*)&sB[k][tx * 4];
            float av[4] = {a.x, a.y, a.z, a.w};
            float bv[4] = {b.x, b.y, b.z, b.w};
            #pragma unroll
            for (int i = 0; i < 4; ++i)
                #pragma unroll
                for (int j = 0; j < 4; ++j)
                    acc[i][j] = fmaf(av[i], bv[j], acc[i][j]);
        }
        __syncthreads();
    }

    #pragma unroll
    for (int i = 0; i < 4; ++i) {
        float4v o = {acc[i][0], acc[i][1], acc[i][2], acc[i][3]};
        *(float4v*)&C[(size_t)(row0 + ty * 4 + i) * VV + col0 + tx * 4] = o;
    }
}

// ---------------------------------------------------------------------------
// Kernel 2: out[b,t,u,v] = enc_proj[b,t,v] + dec_proj[b,u,v]
// One block = one (b,t) pair x half the u-range. enc row held in registers
// (float4/lane); dec rows stream from L2; nontemporal full-line stores.
// Grid: B*T*2 = 2048 blocks, 256 threads (256*4 = V floats per row).
// ---------------------------------------------------------------------------
__global__ __launch_bounds__(256) void bcast_add_kernel(
    const float* __restrict__ enc_proj,
    const float* __restrict__ dec_proj,
    float* __restrict__ out)
{
    const int blk  = blockIdx.x;       // 0..2047
    const int bt   = blk >> 1;         // 0..1023  (b*T + t)
    const int half = blk & 1;
    const int b    = bt >> 9;          // T = 512
    const int tid  = threadIdx.x;
    const int voff = tid * 4;

    float4v e = *(const float4v*)&enc_proj[(size_t)bt * VV + voff];
    const float* dbase = dec_proj + (size_t)b * UU * VV;
    float*       obase = out      + (size_t)bt * UU * VV;

    const int u0 = half * (UU / 2);
    #pragma unroll 4
    for (int u = u0; u < u0 + (UU / 2); ++u) {
        float4v d = *(const float4v*)&dbase[(size_t)u * VV + voff];
        float4v r = e + d;
        __builtin_nontemporal_store(r, (float4v*)&obase[(size_t)u * VV + voff]);
    }
}

extern "C" void kernel_launch(void* const* d_in, const int* in_sizes, int n_in,
                              void* d_out, int out_size, void* d_ws, size_t ws_size,
                              hipStream_t stream) {
    const float* enc = (const float*)d_in[0];   // (2,512,512)  f32
    const float* dec = (const float*)d_in[1];   // (2,128,512)  f32
    const float* W   = (const float*)d_in[2];   // (1024,1024)  f32
    float* out = (float*)d_out;                 // (2,512,128,1024) f32

    float* enc_proj = (float*)d_ws;                       // 1024*1024 f32 = 4 MB
    float* dec_proj = enc_proj + (size_t)BB * TT * VV;    //  256*1024 f32 = 1 MB

    proj_gemm_kernel<<<dim3(320), dim3(256), 0, stream>>>(enc, dec, W, enc_proj, dec_proj);
    bcast_add_kernel<<<dim3(BB * TT * 2), dim3(256), 0, stream>>>(enc_proj, dec_proj, out);
}

// Round 2
// 540.747 us; speedup vs baseline: 1.0276x; 1.0276x over previous
//
#include <hip/hip_runtime.h>

// Problem constants (B,T,U,D,V) = (2,512,128,512,1024)
#define BB 2
#define TT 512
#define UU 128
#define DD 512
#define VV 1024

typedef float float4v __attribute__((ext_vector_type(4)));
typedef float f32x4   __attribute__((ext_vector_type(4)));
typedef short short8  __attribute__((ext_vector_type(8)));

__device__ __forceinline__ unsigned short f2bf(float f) {
    unsigned u = __builtin_bit_cast(unsigned, f);
    unsigned r = (u + 0x7FFFu + ((u >> 16) & 1u)) >> 16;   // RNE
    return (unsigned short)r;
}

__device__ __forceinline__ short8 pack_bf16_8(float4v lo, float4v hi) {
    short8 r;
    r[0] = (short)f2bf(lo.x); r[1] = (short)f2bf(lo.y);
    r[2] = (short)f2bf(lo.z); r[3] = (short)f2bf(lo.w);
    r[4] = (short)f2bf(hi.x); r[5] = (short)f2bf(hi.y);
    r[6] = (short)f2bf(hi.z); r[7] = (short)f2bf(hi.w);
    return r;
}

// ---------------------------------------------------------------------------
// Kernel 1: both projections via bf16 MFMA (fp32->bf16 inline during staging).
//   Cenc[m][v] = sum_k Enc[m][k] * W[v][k]        (m in [0,1024))
//   Cdec[m][v] = sum_k Dec[m][k] * W[v][512+k]    (m in [0,256))
// 64x64 tile, 4 waves, each wave a 32x32 subtile = 2x2 frags of 16x16x32.
// LDS rows padded to 40 bf16 (80 B) -> uniform bank spread for ds_read_b128.
// Grid: 256 enc tiles + 64 dec tiles = 320 blocks.
// ---------------------------------------------------------------------------
__global__ __launch_bounds__(256) void proj_gemm_mfma(
    const float* __restrict__ Aenc,
    const float* __restrict__ Adec,
    const float* __restrict__ W,
    float* __restrict__ Cenc,
    float* __restrict__ Cdec)
{
    __shared__ alignas(16) unsigned short sA[64][40];
    __shared__ alignas(16) unsigned short sB[64][40];

    const int bid = blockIdx.x;
    const float* A; const float* Wp; float* C;
    int tile_m, tile_n;
    if (bid < 256) {
        A = Aenc; Wp = W;      C = Cenc;
        tile_m = bid >> 4; tile_n = bid & 15;
    } else {
        int b2 = bid - 256;
        A = Adec; Wp = W + DD; C = Cdec;   // dec uses W[:, 512:]
        tile_m = b2 >> 4; tile_n = b2 & 15;
    }
    const int row0 = tile_m * 64;
    const int col0 = tile_n * 64;

    const int tid  = threadIdx.x;
    const int lane = tid & 63;
    const int wave = tid >> 6;           // 0..3
    const int wr   = wave >> 1;          // subtile row (0..1)
    const int wc   = wave & 1;           // subtile col (0..1)
    const int lrow = lane & 15;          // fragment row/col within 16
    const int kg   = lane >> 4;          // k-group 0..3

    const int srow = tid >> 2;           // staging row 0..63
    const int schk = tid & 3;            // k-chunk of 8 floats

    f32x4 acc[2][2] = {};

    for (int k0 = 0; k0 < DD; k0 += 32) {
        // issue global loads early (overlap with barrier)
        const float* ap = &A [(size_t)(row0 + srow) * DD      + k0 + schk * 8];
        const float* wp = &Wp[(size_t)(col0 + srow) * (2*DD)  + k0 + schk * 8];
        float4v a0 = *(const float4v*)ap;
        float4v a1 = *(const float4v*)(ap + 4);
        float4v w0 = *(const float4v*)wp;
        float4v w1 = *(const float4v*)(wp + 4);
        short8 av = pack_bf16_8(a0, a1);
        short8 wv = pack_bf16_8(w0, w1);

        __syncthreads();   // previous iteration's fragment reads complete
        *(short8*)&sA[srow][schk * 8] = av;
        *(short8*)&sB[srow][schk * 8] = wv;
        __syncthreads();

        short8 af0 = *(const short8*)&sA[wr * 32 +      lrow][kg * 8];
        short8 af1 = *(const short8*)&sA[wr * 32 + 16 + lrow][kg * 8];
        short8 bf0 = *(const short8*)&sB[wc * 32 +      lrow][kg * 8];
        short8 bf1 = *(const short8*)&sB[wc * 32 + 16 + lrow][kg * 8];

        acc[0][0] = __builtin_amdgcn_mfma_f32_16x16x32_bf16(af0, bf0, acc[0][0], 0, 0, 0);
        acc[0][1] = __builtin_amdgcn_mfma_f32_16x16x32_bf16(af0, bf1, acc[0][1], 0, 0, 0);
        acc[1][0] = __builtin_amdgcn_mfma_f32_16x16x32_bf16(af1, bf0, acc[1][0], 0, 0, 0);
        acc[1][1] = __builtin_amdgcn_mfma_f32_16x16x32_bf16(af1, bf1, acc[1][1], 0, 0, 0);
    }

    // C/D layout (HW-verified): col = lane&15, row = (lane>>4)*4 + reg
    #pragma unroll
    for (int mi = 0; mi < 2; ++mi) {
        #pragma unroll
        for (int ni = 0; ni < 2; ++ni) {
            const int r0 = row0 + wr * 32 + mi * 16 + kg * 4;
            const int c  = col0 + wc * 32 + ni * 16 + lrow;
            #pragma unroll
            for (int j = 0; j < 4; ++j)
                C[(size_t)(r0 + j) * VV + c] = acc[mi][ni][j];
        }
    }
}

// ---------------------------------------------------------------------------
// Kernel 2: out[b,t,u,v] = enc_proj[b,t,v] + dec_proj[b,u,v]
// One block = one (b,t) x half the u-range. enc row in registers; dec rows
// stream from L2; nontemporal full-line float4 stores.
// ---------------------------------------------------------------------------
__global__ __launch_bounds__(256) void bcast_add_kernel(
    const float* __restrict__ enc_proj,
    const float* __restrict__ dec_proj,
    float* __restrict__ out)
{
    const int blk  = blockIdx.x;       // 0..2047
    const int bt   = blk >> 1;         // 0..1023  (b*T + t)
    const int half = blk & 1;
    const int b    = bt >> 9;          // T = 512
    const int tid  = threadIdx.x;
    const int voff = tid * 4;

    float4v e = *(const float4v*)&enc_proj[(size_t)bt * VV + voff];
    const float* dbase = dec_proj + (size_t)b * UU * VV;
    float*       obase = out      + (size_t)bt * UU * VV;

    const int u0 = half * (UU / 2);
    #pragma unroll 4
    for (int u = u0; u < u0 + (UU / 2); ++u) {
        float4v d = *(const float4v*)&dbase[(size_t)u * VV + voff];
        float4v r = e + d;
        __builtin_nontemporal_store(r, (float4v*)&obase[(size_t)u * VV + voff]);
    }
}

extern "C" void kernel_launch(void* const* d_in, const int* in_sizes, int n_in,
                              void* d_out, int out_size, void* d_ws, size_t ws_size,
                              hipStream_t stream) {
    (void)in_sizes; (void)n_in; (void)out_size; (void)ws_size;
    const float* enc = (const float*)d_in[0];   // (2,512,512)  f32
    const float* dec = (const float*)d_in[1];   // (2,128,512)  f32
    const float* W   = (const float*)d_in[2];   // (1024,1024)  f32
    float* out = (float*)d_out;                 // (2,512,128,1024) f32

    float* enc_proj = (float*)d_ws;                       // 1024*1024 f32 = 4 MB
    float* dec_proj = enc_proj + (size_t)BB * TT * VV;    //  256*1024 f32 = 1 MB

    proj_gemm_mfma<<<dim3(320), dim3(256), 0, stream>>>(enc, dec, W, enc_proj, dec_proj);
    bcast_add_kernel<<<dim3(BB * TT * 2), dim3(256), 0, stream>>>(enc_proj, dec_proj, out);
}

// Round 3
// 539.864 us; speedup vs baseline: 1.0293x; 1.0016x over previous
//
#include <hip/hip_runtime.h>

// Problem constants (B,T,U,D,V) = (2,512,128,512,1024)
#define BB 2
#define TT 512
#define UU 128
#define DD 512
#define VV 1024

typedef float float4v __attribute__((ext_vector_type(4)));
typedef float f32x4   __attribute__((ext_vector_type(4)));
typedef short short8  __attribute__((ext_vector_type(8)));

__device__ __forceinline__ unsigned short f2bf(float f) {
    unsigned u = __builtin_bit_cast(unsigned, f);
    unsigned r = (u + 0x7FFFu + ((u >> 16) & 1u)) >> 16;   // RNE
    return (unsigned short)r;
}

__device__ __forceinline__ short8 pack_bf16_8(float4v lo, float4v hi) {
    short8 r;
    r[0] = (short)f2bf(lo.x); r[1] = (short)f2bf(lo.y);
    r[2] = (short)f2bf(lo.z); r[3] = (short)f2bf(lo.w);
    r[4] = (short)f2bf(hi.x); r[5] = (short)f2bf(hi.y);
    r[6] = (short)f2bf(hi.z); r[7] = (short)f2bf(hi.w);
    return r;
}

// ---------------------------------------------------------------------------
// Kernel 1: both projections via bf16 MFMA (fp32->bf16 inline during staging).
//   Cenc[m][v] = sum_k Enc[m][k] * W[v][k]        (m in [0,1024))
//   Cdec[m][v] = sum_k Dec[m][k] * W[v][512+k]    (m in [0,256))
// 64x64 tile, 4 waves, each wave a 32x32 subtile = 2x2 frags of 16x16x32.
// ~5 us; not the bottleneck (measured round 1->2 delta).
// ---------------------------------------------------------------------------
__global__ __launch_bounds__(256) void proj_gemm_mfma(
    const float* __restrict__ Aenc,
    const float* __restrict__ Adec,
    const float* __restrict__ W,
    float* __restrict__ Cenc,
    float* __restrict__ Cdec)
{
    __shared__ alignas(16) unsigned short sA[64][40];
    __shared__ alignas(16) unsigned short sB[64][40];

    const int bid = blockIdx.x;
    const float* A; const float* Wp; float* C;
    int tile_m, tile_n;
    if (bid < 256) {
        A = Aenc; Wp = W;      C = Cenc;
        tile_m = bid >> 4; tile_n = bid & 15;
    } else {
        int b2 = bid - 256;
        A = Adec; Wp = W + DD; C = Cdec;   // dec uses W[:, 512:]
        tile_m = b2 >> 4; tile_n = b2 & 15;
    }
    const int row0 = tile_m * 64;
    const int col0 = tile_n * 64;

    const int tid  = threadIdx.x;
    const int lane = tid & 63;
    const int wave = tid >> 6;           // 0..3
    const int wr   = wave >> 1;          // subtile row (0..1)
    const int wc   = wave & 1;           // subtile col (0..1)
    const int lrow = lane & 15;          // fragment row/col within 16
    const int kg   = lane >> 4;          // k-group 0..3

    const int srow = tid >> 2;           // staging row 0..63
    const int schk = tid & 3;            // k-chunk of 8 floats

    f32x4 acc[2][2] = {};

    for (int k0 = 0; k0 < DD; k0 += 32) {
        const float* ap = &A [(size_t)(row0 + srow) * DD      + k0 + schk * 8];
        const float* wp = &Wp[(size_t)(col0 + srow) * (2*DD)  + k0 + schk * 8];
        float4v a0 = *(const float4v*)ap;
        float4v a1 = *(const float4v*)(ap + 4);
        float4v w0 = *(const float4v*)wp;
        float4v w1 = *(const float4v*)(wp + 4);
        short8 av = pack_bf16_8(a0, a1);
        short8 wv = pack_bf16_8(w0, w1);

        __syncthreads();
        *(short8*)&sA[srow][schk * 8] = av;
        *(short8*)&sB[srow][schk * 8] = wv;
        __syncthreads();

        short8 af0 = *(const short8*)&sA[wr * 32 +      lrow][kg * 8];
        short8 af1 = *(const short8*)&sA[wr * 32 + 16 + lrow][kg * 8];
        short8 bf0 = *(const short8*)&sB[wc * 32 +      lrow][kg * 8];
        short8 bf1 = *(const short8*)&sB[wc * 32 + 16 + lrow][kg * 8];

        acc[0][0] = __builtin_amdgcn_mfma_f32_16x16x32_bf16(af0, bf0, acc[0][0], 0, 0, 0);
        acc[0][1] = __builtin_amdgcn_mfma_f32_16x16x32_bf16(af0, bf1, acc[0][1], 0, 0, 0);
        acc[1][0] = __builtin_amdgcn_mfma_f32_16x16x32_bf16(af1, bf0, acc[1][0], 0, 0, 0);
        acc[1][1] = __builtin_amdgcn_mfma_f32_16x16x32_bf16(af1, bf1, acc[1][1], 0, 0, 0);
    }

    // C/D layout (HW-verified): col = lane&15, row = (lane>>4)*4 + reg
    #pragma unroll
    for (int mi = 0; mi < 2; ++mi) {
        #pragma unroll
        for (int ni = 0; ni < 2; ++ni) {
            const int r0 = row0 + wr * 32 + mi * 16 + kg * 4;
            const int c  = col0 + wc * 32 + ni * 16 + lrow;
            #pragma unroll
            for (int j = 0; j < 4; ++j)
                C[(size_t)(r0 + j) * VV + c] = acc[mi][ni][j];
        }
    }
}

// ---------------------------------------------------------------------------
// Kernel 2 (v2): out[b,t,u,v] = enc_proj[b,t,v] + dec_proj[b,u,v]
// Block = (b, u-quad, t-chunk of 32). The 4 dec rows live in REGISTERS for
// the whole block (read once); inner loop = 1 enc-row load : 4 NT stores.
// Grid: 2 * 32 * 16 = 1024 blocks, 256 threads (256*4 = V floats per row).
// ---------------------------------------------------------------------------
__global__ __launch_bounds__(256) void bcast_add_kernel(
    const float* __restrict__ enc_proj,
    const float* __restrict__ dec_proj,
    float* __restrict__ out)
{
    const int bid = blockIdx.x;            // 0..1023
    const int tc  = bid & 15;              // t-chunk (16 chunks of 32)
    const int uq  = (bid >> 4) & 31;       // u-quad (32 quads of 4)
    const int b   = bid >> 9;              // batch
    const int tid = threadIdx.x;
    const int voff = tid * 4;

    const int u0 = uq * 4;
    float4v d0 = *(const float4v*)&dec_proj[((size_t)(b * UU + u0 + 0)) * VV + voff];
    float4v d1 = *(const float4v*)&dec_proj[((size_t)(b * UU + u0 + 1)) * VV + voff];
    float4v d2 = *(const float4v*)&dec_proj[((size_t)(b * UU + u0 + 2)) * VV + voff];
    float4v d3 = *(const float4v*)&dec_proj[((size_t)(b * UU + u0 + 3)) * VV + voff];

    const int t0 = tc * 32;
    const float* ebase = enc_proj + ((size_t)b * TT) * VV + voff;
    float*       obase = out + (((size_t)b * TT) * UU + u0) * VV + voff;

    #pragma unroll 2
    for (int t = t0; t < t0 + 32; ++t) {
        float4v e = *(const float4v*)&ebase[(size_t)t * VV];
        float* op = obase + (size_t)t * UU * VV;
        __builtin_nontemporal_store(e + d0, (float4v*)(op));
        __builtin_nontemporal_store(e + d1, (float4v*)(op + VV));
        __builtin_nontemporal_store(e + d2, (float4v*)(op + 2 * VV));
        __builtin_nontemporal_store(e + d3, (float4v*)(op + 3 * VV));
    }
}

extern "C" void kernel_launch(void* const* d_in, const int* in_sizes, int n_in,
                              void* d_out, int out_size, void* d_ws, size_t ws_size,
                              hipStream_t stream) {
    (void)in_sizes; (void)n_in; (void)out_size; (void)ws_size;
    const float* enc = (const float*)d_in[0];   // (2,512,512)  f32
    const float* dec = (const float*)d_in[1];   // (2,128,512)  f32
    const float* W   = (const float*)d_in[2];   // (1024,1024)  f32
    float* out = (float*)d_out;                 // (2,512,128,1024) f32

    float* enc_proj = (float*)d_ws;                       // 1024*1024 f32 = 4 MB
    float* dec_proj = enc_proj + (size_t)BB * TT * VV;    //  256*1024 f32 = 1 MB

    proj_gemm_mfma<<<dim3(320), dim3(256), 0, stream>>>(enc, dec, W, enc_proj, dec_proj);
    bcast_add_kernel<<<dim3(1024), dim3(256), 0, stream>>>(enc_proj, dec_proj, out);
}